// Round 11
// baseline (788.154 us; speedup 1.0000x reference)
//
#include <hip/hip_runtime.h>
#include <hip/hip_fp16.h>

typedef _Float16 f16;
typedef _Float16 f16x4 __attribute__((ext_vector_type(4)));
typedef _Float16 f16x8 __attribute__((ext_vector_type(8)));
typedef float f32x4 __attribute__((ext_vector_type(4)));
typedef int i32x4 __attribute__((ext_vector_type(4)));

#define MFMA16(a, b, c) __builtin_amdgcn_mfma_f32_16x16x32_f16((a), (b), (c), 0, 0, 0)
#define MFMAI8(a, b, c) __builtin_amdgcn_mfma_i32_16x16x64_i8((a), (b), (c), 0, 0, 0)

#define FLAG_CAP (1024 * 1024)
#define FLAG_TOL 1e-3f

#define SBAR()   __builtin_amdgcn_s_barrier()
#define SCHEDB() __builtin_amdgcn_sched_barrier(0)

// async global->LDS, 16 B per lane. LDS dest is wave-uniform base (+lane*16);
// global src is per-lane (swizzle baked into source address).
__device__ __forceinline__ void gld16(const void* g, void* l) {
    __builtin_amdgcn_global_load_lds(
        (const __attribute__((address_space(1))) unsigned int*)g,
        (__attribute__((address_space(3))) unsigned int*)l,
        16, 0, 0);
}

// ---------------- scale computation ----------------

__global__ void k_zero(float* p, int* cnt) {
    if (threadIdx.x < 3) p[threadIdx.x] = 0.f;
    if (threadIdx.x == 3) { cnt[0] = 0; cnt[1] = 0; }
}

__global__ void k_absmax(const float* __restrict__ w, int n, float* __restrict__ out) {
    float m = 0.f;
    int stride = gridDim.x * blockDim.x;
    for (int i = blockIdx.x * blockDim.x + threadIdx.x; i < n; i += stride)
        m = fmaxf(m, fabsf(w[i]));
    #pragma unroll
    for (int o = 32; o > 0; o >>= 1) m = fmaxf(m, __shfl_down(m, o));
    __shared__ float sm[4];
    int lane = threadIdx.x & 63, wv = threadIdx.x >> 6;
    if (lane == 0) sm[wv] = m;
    __syncthreads();
    if (threadIdx.x == 0) {
        float mm = fmaxf(fmaxf(sm[0], sm[1]), fmaxf(sm[2], sm[3]));
        atomicMax((unsigned int*)out, __float_as_uint(mm));  // nonneg floats only
    }
}

// W1: fp32 dequant w1dq (fixup) + padded f16 panel q1h [512][832]
__global__ void k_quantw1(const float* __restrict__ w, const float* __restrict__ wmax,
                          float* __restrict__ wdq, f16* __restrict__ q1h) {
    int i = blockIdx.x * blockDim.x + threadIdx.x;
    if (i >= 512 * 832) return;
    int n = i / 832, k = i - n * 832;
    float v = 0.f;
    if (k < 784) {
        float s = wmax[0] / 7.0f + 1e-8f;
        v = rintf(w[n * 784 + k] / s);       // fp32 ops replicate numpy semantics
        v = fminf(fmaxf(v, -7.f), 7.f);
        wdq[n * 784 + k] = v * s;
    }
    q1h[(size_t)n * 832 + k] = (f16)v;
}

// W2: int8 codes + fp32 dequant (fixup)
__global__ void k_quantw2(const float* __restrict__ w, const float* __restrict__ wmax,
                          signed char* __restrict__ q, float* __restrict__ wdq, int n) {
    float s = wmax[0] / 7.0f + 1e-8f;
    int i = blockIdx.x * blockDim.x + threadIdx.x;
    if (i < n) {
        float v = rintf(w[i] / s);
        v = fminf(fmaxf(v, -7.f), 7.f);
        q[i] = (signed char)v;
        if (wdq) wdq[i] = v * s;
    }
}

// W3: int8, zero-padded to 16x512
__global__ void k_quantw3(const float* __restrict__ w, const float* __restrict__ wmax,
                          signed char* __restrict__ q) {
    float s = wmax[0] / 7.0f + 1e-8f;
    int i = blockIdx.x * blockDim.x + threadIdx.x;
    if (i < 16 * 512) {
        float v = 0.f;
        if (i < 10 * 512) {
            v = rintf(w[i] / s);
            v = fminf(fmaxf(v, -7.f), 7.f);
        }
        q[i] = (signed char)v;
    }
}

// ================= DIAGNOSTIC PROBES (write only to scratch) =================
// Round-6 structure (the 440us cold baseline) with memory made INSTANT:
// all gld16 sources collapse to a fixed ~24KB L1/L2-hot window of q1h.
// NODS=1 additionally reads LDS fragments only on tile 0 (regs persist),
// keeping gld16 staging traffic identical. 32 K-tiles, 2048 blocks ->
// 8.4e6 MFMA (1.23x gemm1F) so a slow probe surfaces in top-5.

template <int NODS>
__global__ __launch_bounds__(256, 4) void k_probe(
    const f16* __restrict__ A, const f16* __restrict__ B, float* __restrict__ out)
{
    constexpr int NT = 32;
    __shared__ __align__(16) f16 As[128 * 64];
    __shared__ __align__(16) f16 Bs[128 * 64];

    const int t = threadIdx.x;
    const int lane = t & 63, w = t >> 6;
    const int wr = w >> 1, wc = w & 1;

    f32x4 acc[4][4];
    #pragma unroll
    for (int m = 0; m < 4; ++m)
        #pragma unroll
        for (int n = 0; n < 4; ++n) acc[m][n] = (f32x4){0.f, 0.f, 0.f, 0.f};

    const int lr = lane >> 3;
    const int lc = (((lane & 7) ^ (lane >> 3)) * 8);
    const f16* Ab = A + (size_t)lr * 832 + lc;   // fixed hot window (rows 0..127, k0=0)
    const f16* Bb = B + (size_t)lr * 832 + lc;

    f16x8 af[4], bf[4];                          // persist across tiles when NODS

    for (int tt = 0; tt < NT; ++tt) {
        #pragma unroll
        for (int i = 0; i < 4; ++i) {
            int ch = w * 4 + i;
            gld16(Ab + (size_t)ch * 8 * 832, &As[ch * 512]);
            gld16(Bb + (size_t)ch * 8 * 832, &Bs[ch * 512]);
        }
        __syncthreads();

        #pragma unroll
        for (int kk = 0; kk < 2; ++kk) {
            if (NODS == 0 || tt == 0) {
                int kb = kk * 32 + (lane >> 4) * 8;
                int ksw = kb ^ ((lane & 7) << 3);
                #pragma unroll
                for (int n = 0; n < 4; ++n)
                    bf[n] = *reinterpret_cast<const f16x8*>(&Bs[(wc * 64 + n * 16 + (lane & 15)) * 64 + ksw]);
                #pragma unroll
                for (int m = 0; m < 4; ++m)
                    af[m] = *reinterpret_cast<const f16x8*>(&As[(wr * 64 + m * 16 + (lane & 15)) * 64 + ksw]);
            }
            #pragma unroll
            for (int m = 0; m < 4; ++m)
                #pragma unroll
                for (int n = 0; n < 4; ++n)
                    acc[m][n] = MFMA16(af[m], bf[n], acc[m][n]);
        }
        __syncthreads();
    }

    float s = 0.f;
    #pragma unroll
    for (int m = 0; m < 4; ++m)
        #pragma unroll
        for (int n = 0; n < 4; ++n)
            #pragma unroll
            for (int j = 0; j < 4; ++j) s += acc[m][n][j];
    out[(size_t)blockIdx.x * 256 + t] = s;       // keep live
}

// ========== GEMM1: fused full-N block (128 rows x 512 cols), K=832 ==========
// (unchanged from round 10)

__global__ __launch_bounds__(512, 2) void k_gemm1F(
    const float* __restrict__ X, const f16* __restrict__ B,
    const float* __restrict__ wmax, const float* __restrict__ s1p,
    signed char* __restrict__ A1, int* __restrict__ flagCnt, unsigned* __restrict__ flagList)
{
    constexpr int NT = 13;                   // 832/64 K-tiles
    __shared__ __align__(16) f16 Ah[2][128 * 64];   // 32 KB
    __shared__ __align__(16) f16 Al[2][128 * 64];   // 32 KB
    __shared__ __align__(16) f16 Bt[512 * 64];      // 64 KB

    const int t = threadIdx.x;
    const int lane = t & 63, w = t >> 6;
    const int wr = w >> 2, wc = w & 3;       // 2 x 4 wave grid, wave tile 64x128
    const int l15 = lane & 15, l4 = lane >> 4;
    const int row0 = blockIdx.x * 128;

    f32x4 acc[4][8];
    #pragma unroll
    for (int m = 0; m < 4; ++m)
        #pragma unroll
        for (int n = 0; n < 8; ++n) acc[m][n] = (f32x4){0.f, 0.f, 0.f, 0.f};

    const int lr = lane >> 3;
    const int lc = ((lane & 7) ^ lr) * 8;
    const f16* Bb = B + (size_t)lr * 832 + lc;

    float4 av[4];
    auto LOADA = [&](int tn) {
        #pragma unroll
        for (int i = 0; i < 4; ++i) {
            int f = t + 512 * i;
            int r = f >> 4, s = f & 15;
            int gk = tn * 64 + s * 4;
            av[i] = make_float4(0.f, 0.f, 0.f, 0.f);
            if (gk < 784)
                av[i] = *reinterpret_cast<const float4*>(X + (size_t)(row0 + r) * 784 + gk);
        }
    };
    auto WRITEA = [&](int buf) {
        #pragma unroll
        for (int i = 0; i < 4; ++i) {
            int f = t + 512 * i;
            int r = f >> 4, s = f & 15;
            float vv[4] = {av[i].x, av[i].y, av[i].z, av[i].w};
            f16x4 h0, h1;
            #pragma unroll
            for (int j = 0; j < 4; ++j) {
                f16 c0 = (f16)vv[j];                 // RNE
                h0[j] = c0;
                h1[j] = (f16)(vv[j] - (float)c0);    // exact residual
            }
            int ad = r * 64 + ((s * 4) ^ ((r & 7) << 3));
            *reinterpret_cast<f16x4*>(&Ah[buf][ad]) = h0;
            *reinterpret_cast<f16x4*>(&Al[buf][ad]) = h1;
        }
    };

    LOADA(0);
    asm volatile("s_waitcnt vmcnt(0)" ::: "memory");
    WRITEA(0);

    int cur = 0;
    for (int tt = 0; tt < NT; ++tt) {
        #pragma unroll
        for (int i = 0; i < 8; ++i) {
            int ch = w * 8 + i;
            gld16(Bb + (size_t)ch * 8 * 832 + tt * 64, &Bt[ch * 512]);
        }
        SCHEDB();
        int tn = (tt + 1 < NT) ? tt + 1 : tt;
        LOADA(tn);
        SCHEDB();
        asm volatile("s_waitcnt vmcnt(4)" ::: "memory");
        asm volatile("s_waitcnt lgkmcnt(0)" ::: "memory");
        SBAR();

        #pragma unroll
        for (int kk = 0; kk < 2; ++kk) {
            int kb = kk * 32 + l4 * 8;
            int ksw = kb ^ ((lane & 7) << 3);
            f16x8 fh[4], fl_[4], bf[8];
            #pragma unroll
            for (int m = 0; m < 4; ++m) {
                fh[m]  = *reinterpret_cast<const f16x8*>(&Ah[cur][(wr * 64 + m * 16 + l15) * 64 + ksw]);
                fl_[m] = *reinterpret_cast<const f16x8*>(&Al[cur][(wr * 64 + m * 16 + l15) * 64 + ksw]);
            }
            #pragma unroll
            for (int n = 0; n < 8; ++n)
                bf[n] = *reinterpret_cast<const f16x8*>(&Bt[(wc * 128 + n * 16 + l15) * 64 + ksw]);
            #pragma unroll
            for (int m = 0; m < 4; ++m)
                #pragma unroll
                for (int n = 0; n < 8; ++n) {
                    acc[m][n] = MFMA16(fh[m],  bf[n], acc[m][n]);
                    acc[m][n] = MFMA16(fl_[m], bf[n], acc[m][n]);
                }
        }

        asm volatile("s_waitcnt vmcnt(0)" ::: "memory");
        WRITEA(cur ^ 1);
        SBAR();
        cur ^= 1;
    }

    float sw = wmax[0] / 7.0f + 1e-8f;
    float s1v = s1p[0];
    #pragma unroll
    for (int m = 0; m < 4; ++m)
        #pragma unroll
        for (int n = 0; n < 8; ++n)
            #pragma unroll
            for (int j = 0; j < 4; ++j) {
                int row = row0 + wr * 64 + m * 16 + l4 * 4 + j;
                int col = wc * 128 + n * 16 + l15;
                float h = sw * acc[m][n][j];
                float r = fmaxf(h, 0.f) / s1v;
                float qv = fminf(rintf(r), 15.f);
                A1[(size_t)row * 512 + col] = (signed char)qv;
                float fr = r - floorf(r);
                if (fabsf(fr - 0.5f) < FLAG_TOL) {
                    int p = atomicAdd(flagCnt, 1);
                    if (p < FLAG_CAP) flagList[p] = (unsigned)(row * 512 + col);
                }
            }
}

// ========== GEMM2: full-N i8 block (128 x 512), K=512 (unchanged) ==========

__global__ __launch_bounds__(512, 2) void k_gemm2F(
    const signed char* __restrict__ A, const signed char* __restrict__ B,
    const float* __restrict__ wmax, const float* __restrict__ s1p, const float* __restrict__ s2p,
    signed char* __restrict__ A2, int* __restrict__ flagCnt, unsigned* __restrict__ flagList)
{
    constexpr int NT = 4;
    __shared__ __align__(16) signed char As[2][128 * 128];
    __shared__ __align__(16) signed char Bs[512 * 128];

    const int t = threadIdx.x;
    const int lane = t & 63, w = t >> 6;
    const int wr = w >> 2, wc = w & 3;
    const int l15 = lane & 15, l4 = lane >> 4;
    const int row0 = blockIdx.x * 128;

    i32x4 acc[4][8];
    #pragma unroll
    for (int m = 0; m < 4; ++m)
        #pragma unroll
        for (int n = 0; n < 8; ++n) acc[m][n] = (i32x4){0, 0, 0, 0};

    const int lr = lane >> 3;
    const int lcb = ((lane & 7) ^ lr) * 16;
    const signed char* Ab = A + (size_t)(row0 + lr) * 512 + lcb;
    const signed char* Bb = B + (size_t)lr * 512 + lcb;

    #pragma unroll
    for (int i = 0; i < 2; ++i) {
        int ch = w * 2 + i;
        gld16(Ab + (size_t)ch * 8 * 512, &As[0][ch * 1024]);
    }

    int cur = 0;
    for (int tt = 0; tt < NT; ++tt) {
        #pragma unroll
        for (int i = 0; i < 8; ++i) {
            int ch = w * 8 + i;
            gld16(Bb + (size_t)ch * 8 * 512 + tt * 128, &Bs[ch * 1024]);
        }
        SCHEDB();
        int tn = (tt + 1 < NT) ? tt + 1 : tt;
        #pragma unroll
        for (int i = 0; i < 2; ++i) {
            int ch = w * 2 + i;
            gld16(Ab + (size_t)ch * 8 * 512 + tn * 128, &As[cur ^ 1][ch * 1024]);
        }
        SCHEDB();
        asm volatile("s_waitcnt vmcnt(2)" ::: "memory");
        SBAR();

        #pragma unroll
        for (int kk = 0; kk < 2; ++kk) {
            int sl = kk * 4 + l4;
            int slw = (sl ^ (lane & 7)) * 16;
            i32x4 af[4], bf[8];
            #pragma unroll
            for (int m = 0; m < 4; ++m)
                af[m] = *reinterpret_cast<const i32x4*>(&As[cur][(wr * 64 + m * 16 + l15) * 128 + slw]);
            #pragma unroll
            for (int n = 0; n < 8; ++n)
                bf[n] = *reinterpret_cast<const i32x4*>(&Bs[(wc * 128 + n * 16 + l15) * 128 + slw]);
            #pragma unroll
            for (int m = 0; m < 4; ++m)
                #pragma unroll
                for (int n = 0; n < 8; ++n)
                    acc[m][n] = MFMAI8(af[m], bf[n], acc[m][n]);
        }

        SBAR();
        cur ^= 1;
    }

    double cs = (double)s1p[0] * (double)(wmax[0] / 7.0f + 1e-8f);
    double s2v = (double)s2p[0];
    #pragma unroll
    for (int m = 0; m < 4; ++m)
        #pragma unroll
        for (int n = 0; n < 8; ++n)
            #pragma unroll
            for (int j = 0; j < 4; ++j) {
                int row = row0 + wr * 64 + m * 16 + l4 * 4 + j;
                int col = wc * 128 + n * 16 + l15;
                double r = fmax((double)acc[m][n][j] * cs, 0.0) / s2v;
                double qv = fmin(rint(r), 15.0);
                A2[(size_t)row * 512 + col] = (signed char)qv;
                double fr = r - floor(r);
                if (fabs(fr - 0.5) < (double)FLAG_TOL && r < 16.0) {
                    int p = atomicAdd(flagCnt, 1);
                    if (p < FLAG_CAP) flagList[p] = (unsigned)(row * 512 + col);
                }
            }
}

// ---------------- fixups: BLAS-replicating sequential fp32 FMA ----------------

__global__ void k_fixup1(const float* __restrict__ X, const float* __restrict__ W1dq,
                         const float* __restrict__ s1p,
                         const int* __restrict__ flagCnt, const unsigned* __restrict__ flagList,
                         signed char* __restrict__ A1)
{
    int tid = blockIdx.x * blockDim.x + threadIdx.x;
    int nthr = gridDim.x * blockDim.x;
    int n = flagCnt[0];
    if (n > FLAG_CAP) n = FLAG_CAP;
    float s1 = s1p[0];
    for (int i = tid; i < n; i += nthr) {
        unsigned idx = flagList[i];
        int row = (int)(idx >> 9), col = (int)(idx & 511);
        const float* xr = X + (size_t)row * 784;
        const float* wr = W1dq + (size_t)col * 784;
        float acc = 0.f;
        for (int k = 0; k < 784; ++k)
            acc = fmaf(xr[k], wr[k], acc);       // k-ascending, single acc: BLAS order
        float tq = fmaxf(acc, 0.f) / s1;
        float code = fminf(rintf(tq), 15.f);
        A1[(size_t)row * 512 + col] = (signed char)code;
    }
}

__global__ void k_fixup2(const signed char* __restrict__ A1, const float* __restrict__ W2dq,
                         const float* __restrict__ s1p, const float* __restrict__ s2p,
                         const int* __restrict__ flagCnt, const unsigned* __restrict__ flagList,
                         signed char* __restrict__ A2)
{
    int tid = blockIdx.x * blockDim.x + threadIdx.x;
    int nthr = gridDim.x * blockDim.x;
    int n = flagCnt[0];
    if (n > FLAG_CAP) n = FLAG_CAP;
    float s1 = s1p[0], s2 = s2p[0];
    for (int i = tid; i < n; i += nthr) {
        unsigned idx = flagList[i];
        int row = (int)(idx >> 9), col = (int)(idx & 511);
        const signed char* ar = A1 + (size_t)row * 512;
        const float* wr = W2dq + (size_t)col * 512;
        float acc = 0.f;
        for (int k = 0; k < 512; ++k) {
            float adq = (float)ar[k] * s1;       // fp32 dequant, == ref
            acc = fmaf(adq, wr[k], acc);
        }
        float tq = fmaxf(acc, 0.f) / s2;
        float code = fminf(rintf(tq), 15.f);
        A2[(size_t)row * 512 + col] = (signed char)code;
    }
}

// ---------------- GEMM3: int8 [65536,512] @ [16,512]^T -> fp32 logits ----------------

__global__ __launch_bounds__(256) void k_gemm3i(
    const signed char* __restrict__ A2, const signed char* __restrict__ Q3,
    const float* __restrict__ wmax, const float* __restrict__ s2p,
    float* __restrict__ Out)
{
    __shared__ __align__(16) signed char As[256][80];
    __shared__ __align__(16) signed char Bs[16][80];

    const int t = threadIdx.x;
    const int row0 = blockIdx.x * 256;
    const int lane = t & 63, wv = t >> 6;

    i32x4 acc[4];
    #pragma unroll
    for (int m = 0; m < 4; ++m) acc[m] = (i32x4){0, 0, 0, 0};

    for (int k0 = 0; k0 < 512; k0 += 64) {
        #pragma unroll
        for (int i = 0; i < 4; ++i) {
            int f = t + 256 * i;
            int r = f >> 2, c = f & 3;
            *reinterpret_cast<uint4*>(&As[r][c * 16]) =
                *reinterpret_cast<const uint4*>(A2 + (size_t)(row0 + r) * 512 + k0 + c * 16);
        }
        if (t < 64) {
            int r = t >> 2, c = t & 3;
            *reinterpret_cast<uint4*>(&Bs[r][c * 16]) =
                *reinterpret_cast<const uint4*>(Q3 + (size_t)r * 512 + k0 + c * 16);
        }
        __syncthreads();

        i32x4 bf = *reinterpret_cast<const i32x4*>(&Bs[lane & 15][(lane >> 4) * 16]);
        #pragma unroll
        for (int m = 0; m < 4; ++m) {
            i32x4 af = *reinterpret_cast<const i32x4*>(&As[wv * 64 + m * 16 + (lane & 15)][(lane >> 4) * 16]);
            acc[m] = MFMAI8(af, bf, acc[m]);
        }
        __syncthreads();
    }

    double cs = (double)s2p[0] * (double)(wmax[0] / 7.0f + 1e-8f);
    #pragma unroll
    for (int m = 0; m < 4; ++m)
        #pragma unroll
        for (int j = 0; j < 4; ++j) {
            int row = row0 + wv * 64 + m * 16 + (lane >> 4) * 4 + j;
            int col = lane & 15;
            if (col < 10)
                Out[(size_t)row * 10 + col] = (float)((double)acc[m][j] * cs);
        }
}

// ---------------- launch ----------------

extern "C" void kernel_launch(void* const* d_in, const int* in_sizes, int n_in,
                              void* d_out, int out_size, void* d_ws, size_t ws_size,
                              hipStream_t stream)
{
    (void)in_sizes; (void)n_in; (void)out_size; (void)ws_size;

    const float* X  = (const float*)d_in[0];
    const float* W1 = (const float*)d_in[1];
    const float* W2 = (const float*)d_in[2];
    const float* W3 = (const float*)d_in[3];
    const float* s1 = (const float*)d_in[4];
    const float* s2 = (const float*)d_in[5];
    float* Out = (float*)d_out;

    char* ws = (char*)d_ws;
    float* maxes     = (float*)ws;
    int*   cnts      = (int*)(ws + 16);
    f16*   q1h       = (f16*)(ws + (size_t)(1u << 20));              // 852992 B
    float* w1dq      = (float*)(ws + (size_t)(2u << 20));            // 1605632 B
    float* w2dq      = (float*)(ws + (size_t)(4u << 20));            // 1048576 B
    signed char* q2i = (signed char*)(ws + (size_t)(6u << 20));      // 262144 B
    signed char* q3i = (signed char*)(ws + (size_t)(6u << 20) + 300000);  // 8192 B
    signed char* a1  = (signed char*)(ws + (size_t)(8u << 20));      // 32 MB
    signed char* a2  = (signed char*)(ws + (size_t)(40u << 20));     // 32 MB
    unsigned* fl1    = (unsigned*)(ws + (size_t)(72u << 20));        // 4 MB
    unsigned* fl2    = (unsigned*)(ws + (size_t)(76u << 20));        // 4 MB
    float* probeOut  = (float*)(ws + (size_t)(96u << 20));           // 2x 2 MB (scratch)

    k_zero<<<1, 64, 0, stream>>>(maxes, cnts);
    k_absmax<<<256, 256, 0, stream>>>(W1, 512 * 784, maxes + 0);
    k_absmax<<<256, 256, 0, stream>>>(W2, 512 * 512, maxes + 1);
    k_absmax<<<8, 256, 0, stream>>>(W3, 10 * 512, maxes + 2);
    k_quantw1<<<(512 * 832 + 255) / 256, 256, 0, stream>>>(W1, maxes + 0, w1dq, q1h);
    k_quantw2<<<(512 * 512 + 255) / 256, 256, 0, stream>>>(W2, maxes + 1, q2i, w2dq, 512 * 512);
    k_quantw3<<<(16 * 512 + 255) / 256, 256, 0, stream>>>(W3, maxes + 2, q3i);

    // ---- diagnostic probes (scratch-only; read q1h hot window) ----
    k_probe<0><<<2048, 256, 0, stream>>>(q1h, q1h, probeOut);
    k_probe<1><<<2048, 256, 0, stream>>>(q1h, q1h, probeOut + (size_t)(2048 * 256));

    k_gemm1F<<<512, 512, 0, stream>>>(X, q1h, maxes + 0, s1, a1, cnts + 0, fl1);
    k_fixup1<<<512, 256, 0, stream>>>(X, w1dq, s1, cnts + 0, fl1, a1);
    k_gemm2F<<<512, 512, 0, stream>>>(a1, q2i, maxes + 1, s1, s2, a2, cnts + 1, fl2);
    k_fixup2<<<512, 256, 0, stream>>>(a1, w2dq, s1, s2, cnts + 1, fl2, a2);
    k_gemm3i<<<256, 256, 0, stream>>>(a2, q3i, maxes + 2, s2, Out);
}